// Round 11
// baseline (406.730 us; speedup 1.0000x reference)
//
#include <hip/hip_runtime.h>
#include <hip/hip_fp16.h>
#include <math.h>

#define NN 100000
#define EE 1600000
#define TT 4
#define NLQ 15
#define FDQ 3
#define HCQ 12
#define CAP 48                              // fixed CSR slots per node (max deg+1 <= 48 verified)
#define RECU 8                              // uints per source record (32B: 12 fp16 h + 2 fp32 es)
#define NCB32 ((NN + 31) / 32)              // 3125 node-chunks (32 nodes/block, 8 lanes each) per t
#define BKT 256                             // nodes per dst-bucket (256 -> 50KB LDS, 3 blocks/CU)
#define NBKT ((NN + BKT - 1) / BKT)         // 391 buckets per t
#define BCAP 4608                           // fixed bke slots per bucket (mean 4092, +8 sigma)
#define EB 4096                             // edges per binning block
#define NBE ((EE + EB - 1) / EB)            // 391 binning blocks per t
#define SPB 64                              // stats partial blocks per t

typedef int v4i __attribute__((ext_vector_type(4)));
typedef unsigned v4u __attribute__((ext_vector_type(4)));

__device__ __forceinline__ unsigned pack2(float a, float b) {
    __half2 h = __floats2half2_rn(a, b);
    return *reinterpret_cast<unsigned*>(&h);
}
__device__ __forceinline__ float2 unpack2(unsigned u) {
    __half2 h = *reinterpret_cast<__half2*>(&u);
    return __half22float2(h);
}

// ---------------- stats stage A: 64 blocks/t partial sums -------
__global__ void statsA(const float* __restrict__ req, float* __restrict__ part) {
    int t = blockIdx.y, b = blockIdx.x;
    const float* r = req + (size_t)t * NN;
    const int NP = NN - NLQ;
    __shared__ float ssum[256], ssq[256];
    float s = 0.f, q = 0.f;
    for (int i = b * 256 + threadIdx.x; i < NP; i += SPB * 256) {
        float v = r[NLQ + i]; s += v; q += v * v;
    }
    ssum[threadIdx.x] = s; ssq[threadIdx.x] = q;
    __syncthreads();
    for (int off = 128; off > 0; off >>= 1) {
        if ((int)threadIdx.x < off) {
            ssum[threadIdx.x] += ssum[threadIdx.x + off];
            ssq[threadIdx.x]  += ssq[threadIdx.x + off];
        }
        __syncthreads();
    }
    if (threadIdx.x == 0) {
        part[(t * SPB + b) * 2]     = ssum[0];
        part[(t * SPB + b) * 2 + 1] = ssq[0];
    }
}

// ---------------- stats stage B: fold 64 partials -> mean, 1/std (ddof=1) ----------------
__global__ void statsB(const float* __restrict__ part, float* __restrict__ stats) {
    int t = blockIdx.x, k = threadIdx.x;   // 64 threads
    __shared__ float ssum[64], ssq[64];
    ssum[k] = part[(t * SPB + k) * 2];
    ssq[k]  = part[(t * SPB + k) * 2 + 1];
    __syncthreads();
    for (int off = 32; off > 0; off >>= 1) {
        if (k < off) { ssum[k] += ssum[k + off]; ssq[k] += ssq[k + off]; }
        __syncthreads();
    }
    if (k == 0) {
        float n = (float)(NN - NLQ);
        float mean = ssum[0] / n;
        float var  = (ssq[0] - ssum[0] * mean) / (n - 1.0f);
        stats[t * 2]     = mean;
        stats[t * 2 + 1] = 1.0f / sqrtf(var);
    }
}

// ---------------- fused binning: count -> reserve run -> DIRECT bke write (no staging/scan) ---
// Per-bucket LDS cursor holds ABSOLUTE bke position; L2 write-combines the short runs.
// gcnt must be zeroed first.
__global__ void __launch_bounds__(512) scatF(const int* __restrict__ ei, int* __restrict__ gcnt,
                                             unsigned* __restrict__ bke) {
    int t = blockIdx.y, b = blockIdx.x;
    __shared__ int cnt_[NBKT], cur[NBKT];
    int k = threadIdx.x;                               // 512 threads
    for (int i = k; i < NBKT; i += 512) cnt_[i] = 0;
    __syncthreads();
    int base = b * EB;
    int nvalid = (EE - base < EB) ? (EE - base) : EB;  // always multiple of 4
    int n4 = nvalid >> 2;
    const v4i* dst4p = (const v4i*)(ei + (size_t)t * 2 * EE + EE + base);
    const v4i* src4p = (const v4i*)(ei + (size_t)t * 2 * EE + base);
    v4i dc[2], sc[2];
#pragma unroll
    for (int j = 0; j < 2; j++) {                      // 4 vector loads in flight
        int i4 = j * 512 + k;
        bool v = i4 < n4;
        dc[j] = v ? dst4p[i4] : (v4i)(-1);
        sc[j] = v ? src4p[i4] : (v4i)(0);
    }
#pragma unroll
    for (int j = 0; j < 2; j++)
#pragma unroll
        for (int m = 0; m < 4; m++) {
            int d = dc[j][m];
            if (d >= 0) atomicAdd(&cnt_[d >> 8], 1);
        }
    __syncthreads();
    for (int i = k; i < NBKT; i += 512) {
        int v = cnt_[i];
        int gb = (v > 0) ? atomicAdd(&gcnt[t * NBKT + i], v) : 0;
        cur[i] = i * BCAP + gb;                        // absolute run start for this block
    }
    __syncthreads();
    const size_t tb = (size_t)t * NBKT * BCAP;
#pragma unroll
    for (int j = 0; j < 2; j++)
#pragma unroll
        for (int m = 0; m < 4; m++) {
            int d = dc[j][m];
            if (d >= 0) {
                int lp = atomicAdd(&cur[d >> 8], 1);
                bke[tb + lp] = ((unsigned)(d & 255) << 17) | (unsigned)sc[j][m];
            }
        }
}

// ---------------- stage 4: bucket CSR in LDS; vectorized bke reads; 3 blocks/CU --------------
__global__ void fillv2(const unsigned* __restrict__ bke, const int* __restrict__ gcnt,
                       int* __restrict__ cnt, int* __restrict__ csr) {
    extern __shared__ int sm[];
    int* cl    = sm;            // BKT
    int* slots = sm + BKT;      // BKT*CAP
    int t = blockIdx.y, b = blockIdx.x;
    int nbase = b * BKT;
    int nn = (NN - nbase < BKT) ? (NN - nbase) : BKT;
    for (int i = threadIdx.x; i < nn; i += 256) {
        cl[i] = 1;
        slots[i * CAP] = nbase + i;                // self-loop in slot 0
    }
    __syncthreads();
    int nE  = gcnt[t * NBKT + b];
    int n4  = (nE + 3) >> 2;
    const v4u* bke4 = (const v4u*)(bke + (size_t)t * NBKT * BCAP + (size_t)b * BCAP);
    for (int i4 = threadIdx.x; i4 < n4; i4 += 512) {  // 2 vector loads in flight
        v4u pa = bke4[i4];
        int ib = i4 + 256;
        v4u pb = (ib < n4) ? bke4[ib] : (v4u)(0u);
        int ba = i4 << 2;
#pragma unroll
        for (int j = 0; j < 4; j++) {
            if (ba + j < nE) {
                unsigned p = pa[j];
                int dl = p >> 17, src = (int)(p & 0x1FFFF);
                int pos = atomicAdd(&cl[dl], 1);
                slots[dl * CAP + pos] = src;
            }
        }
        int bb = ib << 2;
#pragma unroll
        for (int j = 0; j < 4; j++) {
            if (bb + j < nE) {
                unsigned p = pb[j];
                int dl = p >> 17, src = (int)(p & 0x1FFFF);
                int pos = atomicAdd(&cl[dl], 1);
                slots[dl * CAP + pos] = src;
            }
        }
    }
    __syncthreads();
    // stream slots 0..31 of every node (8 of 12 v4i per row); cached (re-read by 4 edge passes)
    const v4i* sl4 = (const v4i*)slots;
    v4i* dst4 = (v4i*)(csr + ((size_t)t * NN + nbase) * CAP);
    for (int i = threadIdx.x; i < nn * 8; i += 256) {
        int node = i >> 3, w = i & 7;
        dst4[node * 12 + w] = sl4[node * 12 + w];
    }
    for (int i = threadIdx.x; i < nn; i += 256) {
        if (cl[i] > 32) {
#pragma unroll
            for (int w = 8; w < 12; w++)
                dst4[i * 12 + w] = sl4[i * 12 + w];
        }
    }
    for (int i = threadIdx.x; i < nn; i += 256)
        cnt[t * NN + nbase + i] = cl[i];
}

// ---------------- layer-0 node kernel: build x (5 dims) inline, write 32B record ----------------
__global__ void node0_kernel(const int* __restrict__ nt, const float* __restrict__ req,
                             const float* __restrict__ ti, const float* __restrict__ emb,
                             const float* __restrict__ W, const float* __restrict__ as_,
                             const float* __restrict__ ad_, const float* __restrict__ stats,
                             unsigned* __restrict__ hrec, float* __restrict__ ed) {
    __shared__ float sW[5 * HCQ], sas[HCQ], sad[HCQ];
    if (threadIdx.x < 5 * HCQ) sW[threadIdx.x] = W[threadIdx.x];
    if (threadIdx.x < HCQ) { sas[threadIdx.x] = as_[threadIdx.x]; sad[threadIdx.x] = ad_[threadIdx.x]; }
    __syncthreads();
    int id = blockIdx.x * blockDim.x + threadIdx.x;
    if (id >= TT * NN) return;
    int t = id / NN, n = id - t * NN;
    float mean = stats[t * 2], rstd = stats[t * 2 + 1];
    int typ = nt[id];
    float x[5];
    x[0] = emb[typ * FDQ + 0];
    x[1] = emb[typ * FDQ + 1];
    x[2] = emb[typ * FDQ + 2];
    float rv = req[id];
    x[3] = (n < NLQ) ? rv : (rv - mean) * rstd;
    x[4] = ti[id];
    float hv[HCQ];
#pragma unroll
    for (int c = 0; c < HCQ; c++) {
        float a = 0.f;
#pragma unroll
        for (int k = 0; k < 5; k++) a += x[k] * sW[k * HCQ + c];
        hv[c] = a;
    }
    float e0 = 0.f, e1 = 0.f, f0 = 0.f, f1 = 0.f;
#pragma unroll
    for (int c = 0; c < 6; c++) {
        e0 += hv[c] * sas[c];     f0 += hv[c] * sad[c];
        e1 += hv[6 + c] * sas[6 + c]; f1 += hv[6 + c] * sad[6 + c];
    }
    uint4* rp = (uint4*)(hrec + (size_t)id * RECU);
    rp[0] = make_uint4(pack2(hv[0], hv[1]), pack2(hv[2], hv[3]), pack2(hv[4], hv[5]), pack2(hv[6], hv[7]));
    rp[1] = make_uint4(pack2(hv[8], hv[9]), pack2(hv[10], hv[11]), __float_as_uint(e0), __float_as_uint(e1));
    ((float2*)ed)[id] = make_float2(f0, f1);
}

// ---------------- fused edge pass + next-layer node transform (unchanged) ---------------------
__global__ void edge_kernel(const int* __restrict__ cnt, const int* __restrict__ csr_src,
                            const unsigned* __restrict__ hrecI, const float* __restrict__ edI,
                            const float* __restrict__ bias,
                            const float* __restrict__ Wn, const float* __restrict__ asn,
                            const float* __restrict__ adn,
                            unsigned* __restrict__ hrecO, float* __restrict__ edO,
                            float* __restrict__ outF, int mode) {
    __shared__ float sb[HCQ], sW[HCQ * HCQ], sas[HCQ], sad[HCQ];
    if (threadIdx.x < HCQ) sb[threadIdx.x] = bias[threadIdx.x];
    if (mode == 0) {
        if (threadIdx.x < HCQ * HCQ) sW[threadIdx.x] = Wn[threadIdx.x];
        if (threadIdx.x < HCQ) { sas[threadIdx.x] = asn[threadIdx.x]; sad[threadIdx.x] = adn[threadIdx.x]; }
    }
    __syncthreads();
    int b = blockIdx.x;
    int t = b & 3;                                   // keeps t == XCD & 3 affinity
    int nl = threadIdx.x >> 3, q = threadIdx.x & 7;
    int n = (b >> 2) * 32 + nl;
    if (n >= NN) return;                             // whole octet exits together
    int id = t * NN + n;
    int deg = cnt[id];
    const int*      srcs = csr_src + (size_t)id * CAP;   // 192B-aligned rows
    const unsigned* hb   = hrecI + (size_t)t * NN * RECU;
    float2 edv = ((const float2*)edI)[id];
    float ed0 = edv.x, ed1 = edv.y;
    float d0 = 0.f, d1 = 0.f;
    float acc[HCQ];
#pragma unroll
    for (int c = 0; c < HCQ; c++) acc[c] = 0.f;

    auto process = [&](int4 s4, int ebase) {
        int rem = deg - ebase;                        // >= 1 at every call site
        int ss[4];
        ss[0] = s4.x; ss[1] = s4.y; ss[2] = s4.z; ss[3] = s4.w;
        uint4 ra[4], rb[4];
#pragma unroll
        for (int k = 0; k < 4; k++) {                 // miss slots: h=0, es=-inf -> w=exp(-inf)=0
            ra[k] = make_uint4(0u, 0u, 0u, 0u);
            rb[k] = make_uint4(0u, 0u, 0xFF800000u, 0xFF800000u);
        }
#pragma unroll
        for (int k = 0; k < 4; k++) {                 // predicated: masked lanes issue no requests
            if (rem > k) {
                const uint4* hp = (const uint4*)(hb + (size_t)ss[k] * RECU);
                ra[k] = hp[0];
                rb[k] = hp[1];
            }
        }
#pragma unroll
        for (int k = 0; k < 4; k++) {
            float l0 = __uint_as_float(rb[k].z) + ed0; l0 = fmaxf(l0, 0.2f * l0);
            float l1 = __uint_as_float(rb[k].w) + ed1; l1 = fmaxf(l1, 0.2f * l1);
            float w0 = __expf(l0), w1 = __expf(l1);
            d0 += w0; d1 += w1;
            float2 h01 = unpack2(ra[k].x), h23 = unpack2(ra[k].y), h45 = unpack2(ra[k].z);
            float2 h67 = unpack2(ra[k].w), h89 = unpack2(rb[k].x), hab = unpack2(rb[k].y);
            acc[0] += w0 * h01.x;  acc[1] += w0 * h01.y;
            acc[2] += w0 * h23.x;  acc[3] += w0 * h23.y;
            acc[4] += w0 * h45.x;  acc[5] += w0 * h45.y;
            acc[6] += w1 * h67.x;  acc[7] += w1 * h67.y;
            acc[8]  += w1 * h89.x; acc[9]  += w1 * h89.y;
            acc[10] += w1 * hab.x; acc[11] += w1 * hab.y;
        }
    };

    int e0s = q * 4;
    if (e0s < deg) {                                  // CSR load also predicated
        int4 sA = *(const int4*)(srcs + e0s);
        process(sA, e0s);
    }
    if (q < 4) {                                      // rare tail: deg>32 (~2e-4 of nodes)
        int e2 = 32 + q * 4;
        if (e2 < deg) {
            int4 sC = *(const int4*)(srcs + e2);
            process(sC, e2);
        }
    }

    // octet reduction: 14 partials x 3 xor rounds -> ALL lanes hold full sums
#pragma unroll
    for (int m = 1; m <= 4; m <<= 1) {
        d0 += __shfl_xor(d0, m);
        d1 += __shfl_xor(d1, m);
#pragma unroll
        for (int c = 0; c < HCQ; c++) acc[c] += __shfl_xor(acc[c], m);
    }

    float inv0 = 1.0f / (d0 + 1e-16f);
    float inv1 = 1.0f / (d1 + 1e-16f);
    float ov[HCQ];
#pragma unroll
    for (int c = 0; c < HCQ; c++)
        ov[c] = acc[c] * ((c < 6) ? inv0 : inv1) + sb[c];

    if (mode == 1) {
        if (q < 3) {                                  // 3 lanes x float4, coalesced
            float4* op = (float4*)(outF + (size_t)id * HCQ);
            op[q] = make_float4(ov[4 * q], ov[4 * q + 1], ov[4 * q + 2], ov[4 * q + 3]);
        }
        return;
    }
#pragma unroll
    for (int c = 0; c < HCQ; c++) ov[c] = fmaxf(ov[c], 0.f);
    // lane q<6 computes channel pair (2q, 2q+1); lanes 6,7 compute a dummy pair (cc=0)
    int cc = (q < 6) ? 2 * q : 0;
    float hv0 = 0.f, hv1 = 0.f;
#pragma unroll
    for (int k = 0; k < HCQ; k++) {
        hv0 += ov[k] * sW[k * HCQ + cc];
        hv1 += ov[k] * sW[k * HCQ + cc + 1];
    }
    float pe = hv0 * sas[cc] + hv1 * sas[cc + 1];
    float pf = hv0 * sad[cc] + hv1 * sad[cc + 1];
    if (q >= 6) { pe = 0.f; pf = 0.f; }
    // head sums across the octet (width-8 shuffles): head0 = lanes 0..2, head1 = lanes 3..5
    float e0h = __shfl(pe, 0, 8) + __shfl(pe, 1, 8) + __shfl(pe, 2, 8);
    float e1h = __shfl(pe, 3, 8) + __shfl(pe, 4, 8) + __shfl(pe, 5, 8);
    float f0h = __shfl(pf, 0, 8) + __shfl(pf, 1, 8) + __shfl(pf, 2, 8);
    float f1h = __shfl(pf, 3, 8) + __shfl(pf, 4, 8) + __shfl(pf, 5, 8);
    unsigned word;
    if (q < 6)      word = pack2(hv0, hv1);           // record words 0..5 (12 fp16 h)
    else if (q == 6) word = __float_as_uint(e0h);     // word 6: e0
    else             word = __float_as_uint(e1h);     // word 7: e1
    hrecO[(size_t)id * RECU + q] = word;              // 8 lanes x 4B = full 32B record, coalesced
    if (q == 0) ((float2*)edO)[id] = make_float2(f0h, f1h);
}

extern "C" void kernel_launch(void* const* d_in, const int* in_sizes, int n_in,
                              void* d_out, int out_size, void* d_ws, size_t ws_size,
                              hipStream_t stream) {
    const int*   nt  = (const int*)d_in[0];
    const float* req = (const float*)d_in[1];
    const float* ti  = (const float*)d_in[2];
    const int*   ei  = (const int*)d_in[3];
    const float* emb = (const float*)d_in[4];
    const float* W[4], *as_[4], *ad_[4], *bb[4];
    for (int l = 0; l < 4; l++) {
        W[l]   = (const float*)d_in[5 + l * 4 + 0];
        as_[l] = (const float*)d_in[5 + l * 4 + 1];
        ad_[l] = (const float*)d_in[5 + l * 4 + 2];
        bb[l]  = (const float*)d_in[5 + l * 4 + 3];
    }

    char* p = (char*)d_ws;
    auto alloc = [&](size_t bytes) -> void* {
        void* r = (void*)p;
        p += (bytes + 255) & ~(size_t)255;
        return r;
    };
    float*    stats = (float*)alloc((size_t)TT * 2 * 4);
    float*    part  = (float*)alloc((size_t)TT * SPB * 2 * 4);
    int*      cnt   = (int*)  alloc((size_t)TT * NN * 4);
    unsigned* hrecA = (unsigned*)alloc((size_t)TT * NN * RECU * 4);
    float*    edA   = (float*)alloc((size_t)TT * NN * 2 * 4);
    int*      gcnt  = (int*)  alloc((size_t)TT * NBKT * 4);
    // bke (28.8MB) dies at fillv2; hrecB/edB (16MB) born at edge pass 0 — alias them
    char*     ub    = (char*)alloc((size_t)TT * NBKT * BCAP * 4);
    unsigned* bke   = (unsigned*)ub;
    unsigned* hrecB = (unsigned*)ub;
    float*    edB   = (float*)(ub + (size_t)TT * NN * RECU * 4);
    int*      csr   = (int*)  alloc((size_t)TT * NN * CAP * 4);   // 76.8 MB, last

    hipMemsetAsync(gcnt, 0, (size_t)TT * NBKT * 4, stream);

    statsA<<<dim3(SPB, TT), 256, 0, stream>>>(req, part);
    statsB<<<TT, 64, 0, stream>>>(part, stats);

    scatF<<<dim3(NBE, TT), 512, 0, stream>>>(ei, gcnt, bke);
    size_t fillLds = (size_t)(BKT + BKT * CAP) * 4;   // 50,176 B -> 3 blocks/CU
    fillv2<<<dim3(NBKT, TT), 256, fillLds, stream>>>(bke, gcnt, cnt, csr);

    int ngrid = (TT * NN + 255) / 256;
    int egrid2 = 4 * NCB32;
    node0_kernel<<<ngrid, 256, 0, stream>>>(nt, req, ti, emb, W[0], as_[0], ad_[0], stats, hrecA, edA);
    // edge l reads buffer (l even -> A, odd -> B), writes the other; l=3 writes d_out
    edge_kernel<<<egrid2, 256, 0, stream>>>(cnt, csr, hrecA, edA, bb[0], W[1], as_[1], ad_[1],
                                            hrecB, edB, nullptr, 0);
    edge_kernel<<<egrid2, 256, 0, stream>>>(cnt, csr, hrecB, edB, bb[1], W[2], as_[2], ad_[2],
                                            hrecA, edA, nullptr, 0);
    edge_kernel<<<egrid2, 256, 0, stream>>>(cnt, csr, hrecA, edA, bb[2], W[3], as_[3], ad_[3],
                                            hrecB, edB, nullptr, 0);
    edge_kernel<<<egrid2, 256, 0, stream>>>(cnt, csr, hrecB, edB, bb[3], nullptr, nullptr, nullptr,
                                            nullptr, nullptr, (float*)d_out, 1);
}

// Round 12
// 401.907 us; speedup vs baseline: 1.0120x; 1.0120x over previous
//
#include <hip/hip_runtime.h>
#include <hip/hip_fp16.h>
#include <math.h>

#define NN 100000
#define EE 1600000
#define TT 4
#define NLQ 15
#define FDQ 3
#define HCQ 12
#define CAP 48                              // fixed CSR slots per node (max deg+1 <= 48 verified)
#define RECU 8                              // uints per source record (32B: 12 fp16 h + 2 fp32 es)
#define NCB32 ((NN + 31) / 32)              // 3125 node-chunks (32 nodes/block, 8 lanes each) per t
#define BKT 512                             // nodes per dst-bucket
#define NBKT ((NN + BKT - 1) / BKT)         // 196 buckets per t
#define BCAP 9216                           // fixed bke slots per bucket (mean 8192, +11 sigma safe)
#define EB 4096                             // edges per binning block
#define NBE ((EE + EB - 1) / EB)            // 391 binning blocks per t
#define SPB 64                              // stats partial blocks per t
#define L2E 1.4426950408889634f             // log2(e): folded into es/ed so loop uses exp2f

typedef int v4i __attribute__((ext_vector_type(4)));
typedef unsigned v4u __attribute__((ext_vector_type(4)));

__device__ __forceinline__ unsigned pack2(float a, float b) {
    __half2 h = __floats2half2_rn(a, b);
    return *reinterpret_cast<unsigned*>(&h);
}
__device__ __forceinline__ float2 unpack2(unsigned u) {
    __half2 h = *reinterpret_cast<__half2*>(&u);
    return __half22float2(h);
}

// ---------------- stats stage A: 64 blocks/t partial sums -------
__global__ void statsA(const float* __restrict__ req, float* __restrict__ part) {
    int t = blockIdx.y, b = blockIdx.x;
    const float* r = req + (size_t)t * NN;
    const int NP = NN - NLQ;
    __shared__ float ssum[256], ssq[256];
    float s = 0.f, q = 0.f;
    for (int i = b * 256 + threadIdx.x; i < NP; i += SPB * 256) {
        float v = r[NLQ + i]; s += v; q += v * v;
    }
    ssum[threadIdx.x] = s; ssq[threadIdx.x] = q;
    __syncthreads();
    for (int off = 128; off > 0; off >>= 1) {
        if ((int)threadIdx.x < off) {
            ssum[threadIdx.x] += ssum[threadIdx.x + off];
            ssq[threadIdx.x]  += ssq[threadIdx.x + off];
        }
        __syncthreads();
    }
    if (threadIdx.x == 0) {
        part[(t * SPB + b) * 2]     = ssum[0];
        part[(t * SPB + b) * 2 + 1] = ssq[0];
    }
}

// ---------------- stats stage B: fold 64 partials -> mean, 1/std (ddof=1) ----------------
__global__ void statsB(const float* __restrict__ part, float* __restrict__ stats) {
    int t = blockIdx.x, k = threadIdx.x;   // 64 threads
    __shared__ float ssum[64], ssq[64];
    ssum[k] = part[(t * SPB + k) * 2];
    ssq[k]  = part[(t * SPB + k) * 2 + 1];
    __syncthreads();
    for (int off = 32; off > 0; off >>= 1) {
        if (k < off) { ssum[k] += ssum[k + off]; ssq[k] += ssq[k + off]; }
        __syncthreads();
    }
    if (k == 0) {
        float n = (float)(NN - NLQ);
        float mean = ssum[0] / n;
        float var  = (ssq[0] - ssum[0] * mean) / (n - 1.0f);
        stats[t * 2]     = mean;
        stats[t * 2 + 1] = 1.0f / sqrtf(var);
    }
}

// ---------------- fused binning: VECTORIZED count + LDS sort + atomic bucket-run alloc ------
// (R10 configuration — staged coalesced writes; gcnt must be zeroed first.)
__global__ void scatF(const int* __restrict__ ei, int* __restrict__ gcnt,
                      unsigned* __restrict__ bke) {
    int t = blockIdx.y, b = blockIdx.x;
    __shared__ unsigned sorted[EB];
    __shared__ unsigned char bid[EB];
    __shared__ int cnt_[NBKT], cur[NBKT], goff[NBKT];
    __shared__ int sv[256];
    int k = threadIdx.x;
    for (int i = k; i < NBKT; i += 256) cnt_[i] = 0;
    __syncthreads();
    int base = b * EB;
    int nvalid = (EE - base < EB) ? (EE - base) : EB;   // always multiple of 4
    int n4 = nvalid >> 2;
    const v4i* dst4p = (const v4i*)(ei + (size_t)t * 2 * EE + EE + base);
    const v4i* src4p = (const v4i*)(ei + (size_t)t * 2 * EE + base);
    v4i dc[4];
#pragma unroll
    for (int j = 0; j < 4; j++) {                     // 4 vector loads in flight
        int i4 = j * 256 + k;
        dc[j] = (i4 < n4) ? dst4p[i4] : (v4i)(-1);
    }
#pragma unroll
    for (int j = 0; j < 4; j++)
#pragma unroll
        for (int m = 0; m < 4; m++) {
            int d = dc[j][m];
            if (d >= 0) atomicAdd(&cnt_[d >> 9], 1);
        }
    __syncthreads();
    int v = (k < NBKT) ? cnt_[k] : 0;
    sv[k] = v;
    __syncthreads();
    for (int off = 1; off < 256; off <<= 1) {         // 196-wide exclusive scan
        int x = (k >= off) ? sv[k - off] : 0;
        __syncthreads();
        sv[k] += x;
        __syncthreads();
    }
    if (k < NBKT) {
        int ex = sv[k] - v;
        cur[k]  = ex;
        int gb = atomicAdd(&gcnt[t * NBKT + k], v);   // reserve this block's run in bucket k
        goff[k] = k * BCAP + gb - ex;
    }
    __syncthreads();
#pragma unroll
    for (int j = 0; j < 4; j++) {
        int i4 = j * 256 + k;
        if (i4 < n4) {
            v4i s4 = src4p[i4];
#pragma unroll
            for (int m = 0; m < 4; m++) {
                int d = dc[j][m];
                int bk = d >> 9;
                int lp = atomicAdd(&cur[bk], 1);
                sorted[lp] = ((unsigned)(d & 511) << 17) | (unsigned)s4[m];
                bid[lp] = (unsigned char)bk;
            }
        }
    }
    __syncthreads();
    const size_t tb = (size_t)t * NBKT * BCAP;
    for (int p = k; p < nvalid; p += 256) {           // bucket-run writes, naturally coalesced
        int B = bid[p];
        bke[tb + goff[B] + p] = sorted[p];
    }
}

// ---------------- stage 4: bucket CSR in LDS; VECTORIZED bke reads (16B-aligned buckets) ------
__global__ void fillv2(const unsigned* __restrict__ bke, const int* __restrict__ gcnt,
                       int* __restrict__ cnt, int* __restrict__ csr) {
    extern __shared__ int sm[];
    int* cl    = sm;            // BKT
    int* slots = sm + BKT;      // BKT*CAP
    int t = blockIdx.y, b = blockIdx.x;
    int nbase = b * BKT;
    int nn = (NN - nbase < BKT) ? (NN - nbase) : BKT;
    for (int i = threadIdx.x; i < nn; i += 256) {
        cl[i] = 1;
        slots[i * CAP] = nbase + i;                // self-loop in slot 0
    }
    __syncthreads();
    int nE  = gcnt[t * NBKT + b];
    int n4  = (nE + 3) >> 2;
    const v4u* bke4 = (const v4u*)(bke + (size_t)t * NBKT * BCAP + (size_t)b * BCAP);
    for (int i4 = threadIdx.x; i4 < n4; i4 += 512) {  // 2 vector loads in flight
        v4u pa = bke4[i4];
        int ib = i4 + 256;
        v4u pb = (ib < n4) ? bke4[ib] : (v4u)(0u);
        int ba = i4 << 2;
#pragma unroll
        for (int j = 0; j < 4; j++) {
            if (ba + j < nE) {
                unsigned p = pa[j];
                int dl = p >> 17, src = (int)(p & 0x1FFFF);
                int pos = atomicAdd(&cl[dl], 1);
                slots[dl * CAP + pos] = src;
            }
        }
        int bb = ib << 2;
#pragma unroll
        for (int j = 0; j < 4; j++) {
            if (bb + j < nE) {
                unsigned p = pb[j];
                int dl = p >> 17, src = (int)(p & 0x1FFFF);
                int pos = atomicAdd(&cl[dl], 1);
                slots[dl * CAP + pos] = src;
            }
        }
    }
    __syncthreads();
    // stream slots 0..31 of every node (8 of 12 v4i per row); cached (re-read by 4 edge passes)
    const v4i* sl4 = (const v4i*)slots;
    v4i* dst4 = (v4i*)(csr + ((size_t)t * NN + nbase) * CAP);
    for (int i = threadIdx.x; i < nn * 8; i += 256) {
        int node = i >> 3, w = i & 7;
        dst4[node * 12 + w] = sl4[node * 12 + w];
    }
    for (int i = threadIdx.x; i < nn; i += 256) {
        if (cl[i] > 32) {
#pragma unroll
            for (int w = 8; w < 12; w++)
                dst4[i * 12 + w] = sl4[i * 12 + w];
        }
    }
    for (int i = threadIdx.x; i < nn; i += 256)
        cnt[t * NN + nbase + i] = cl[i];
}

// ---------------- layer-0 node kernel: es/ed pre-scaled by log2(e) ----------------
__global__ void node0_kernel(const int* __restrict__ nt, const float* __restrict__ req,
                             const float* __restrict__ ti, const float* __restrict__ emb,
                             const float* __restrict__ W, const float* __restrict__ as_,
                             const float* __restrict__ ad_, const float* __restrict__ stats,
                             unsigned* __restrict__ hrec, float* __restrict__ ed) {
    __shared__ float sW[5 * HCQ], sas[HCQ], sad[HCQ];
    if (threadIdx.x < 5 * HCQ) sW[threadIdx.x] = W[threadIdx.x];
    if (threadIdx.x < HCQ) { sas[threadIdx.x] = as_[threadIdx.x]; sad[threadIdx.x] = ad_[threadIdx.x]; }
    __syncthreads();
    int id = blockIdx.x * blockDim.x + threadIdx.x;
    if (id >= TT * NN) return;
    int t = id / NN, n = id - t * NN;
    float mean = stats[t * 2], rstd = stats[t * 2 + 1];
    int typ = nt[id];
    float x[5];
    x[0] = emb[typ * FDQ + 0];
    x[1] = emb[typ * FDQ + 1];
    x[2] = emb[typ * FDQ + 2];
    float rv = req[id];
    x[3] = (n < NLQ) ? rv : (rv - mean) * rstd;
    x[4] = ti[id];
    float hv[HCQ];
#pragma unroll
    for (int c = 0; c < HCQ; c++) {
        float a = 0.f;
#pragma unroll
        for (int k = 0; k < 5; k++) a += x[k] * sW[k * HCQ + c];
        hv[c] = a;
    }
    float e0 = 0.f, e1 = 0.f, f0 = 0.f, f1 = 0.f;
#pragma unroll
    for (int c = 0; c < 6; c++) {
        e0 += hv[c] * sas[c];     f0 += hv[c] * sad[c];
        e1 += hv[6 + c] * sas[6 + c]; f1 += hv[6 + c] * sad[6 + c];
    }
    e0 *= L2E; e1 *= L2E; f0 *= L2E; f1 *= L2E;       // leaky(x)*c == leaky(x*c), c>0
    uint4* rp = (uint4*)(hrec + (size_t)id * RECU);
    rp[0] = make_uint4(pack2(hv[0], hv[1]), pack2(hv[2], hv[3]), pack2(hv[4], hv[5]), pack2(hv[6], hv[7]));
    rp[1] = make_uint4(pack2(hv[8], hv[9]), pack2(hv[10], hv[11]), __float_as_uint(e0), __float_as_uint(e1));
    ((float2*)ed)[id] = make_float2(f0, f1);
}

// ---------------- fused edge pass + next-layer node transform ----------------
// 8 lanes per dst node, predicated loads, -inf sentinel, exp2f (log2e pre-folded).
__global__ void edge_kernel(const int* __restrict__ cnt, const int* __restrict__ csr_src,
                            const unsigned* __restrict__ hrecI, const float* __restrict__ edI,
                            const float* __restrict__ bias,
                            const float* __restrict__ Wn, const float* __restrict__ asn,
                            const float* __restrict__ adn,
                            unsigned* __restrict__ hrecO, float* __restrict__ edO,
                            float* __restrict__ outF, int mode) {
    __shared__ float sb[HCQ], sW[HCQ * HCQ], sas[HCQ], sad[HCQ];
    if (threadIdx.x < HCQ) sb[threadIdx.x] = bias[threadIdx.x];
    if (mode == 0) {
        if (threadIdx.x < HCQ * HCQ) sW[threadIdx.x] = Wn[threadIdx.x];
        if (threadIdx.x < HCQ) { sas[threadIdx.x] = asn[threadIdx.x]; sad[threadIdx.x] = adn[threadIdx.x]; }
    }
    __syncthreads();
    int b = blockIdx.x;
    int t = b & 3;                                   // keeps t == XCD & 3 affinity
    int nl = threadIdx.x >> 3, q = threadIdx.x & 7;
    int n = (b >> 2) * 32 + nl;
    if (n >= NN) return;                             // whole octet exits together
    int id = t * NN + n;
    int deg = cnt[id];
    const int*      srcs = csr_src + (size_t)id * CAP;   // 192B-aligned rows
    const unsigned* hb   = hrecI + (size_t)t * NN * RECU;
    float2 edv = ((const float2*)edI)[id];
    float ed0 = edv.x, ed1 = edv.y;
    float d0 = 0.f, d1 = 0.f;
    float acc[HCQ];
#pragma unroll
    for (int c = 0; c < HCQ; c++) acc[c] = 0.f;

    auto process = [&](int4 s4, int ebase) {
        int rem = deg - ebase;                        // >= 1 at every call site
        int ss[4];
        ss[0] = s4.x; ss[1] = s4.y; ss[2] = s4.z; ss[3] = s4.w;
        uint4 ra[4], rb[4];
#pragma unroll
        for (int k = 0; k < 4; k++) {                 // miss slots: h=0, es=-inf -> w=exp2(-inf)=0
            ra[k] = make_uint4(0u, 0u, 0u, 0u);
            rb[k] = make_uint4(0u, 0u, 0xFF800000u, 0xFF800000u);
        }
#pragma unroll
        for (int k = 0; k < 4; k++) {                 // predicated: masked lanes issue no requests
            if (rem > k) {
                const uint4* hp = (const uint4*)(hb + (size_t)ss[k] * RECU);
                ra[k] = hp[0];
                rb[k] = hp[1];
            }
        }
#pragma unroll
        for (int k = 0; k < 4; k++) {
            float l0 = __uint_as_float(rb[k].z) + ed0; l0 = fmaxf(l0, 0.2f * l0);
            float l1 = __uint_as_float(rb[k].w) + ed1; l1 = fmaxf(l1, 0.2f * l1);
            float w0 = exp2f(l0), w1 = exp2f(l1);     // log2e folded at producer
            d0 += w0; d1 += w1;
            float2 h01 = unpack2(ra[k].x), h23 = unpack2(ra[k].y), h45 = unpack2(ra[k].z);
            float2 h67 = unpack2(ra[k].w), h89 = unpack2(rb[k].x), hab = unpack2(rb[k].y);
            acc[0] += w0 * h01.x;  acc[1] += w0 * h01.y;
            acc[2] += w0 * h23.x;  acc[3] += w0 * h23.y;
            acc[4] += w0 * h45.x;  acc[5] += w0 * h45.y;
            acc[6] += w1 * h67.x;  acc[7] += w1 * h67.y;
            acc[8]  += w1 * h89.x; acc[9]  += w1 * h89.y;
            acc[10] += w1 * hab.x; acc[11] += w1 * hab.y;
        }
    };

    int e0s = q * 4;
    if (e0s < deg) {                                  // CSR load also predicated
        int4 sA = *(const int4*)(srcs + e0s);
        process(sA, e0s);
    }
    if (q < 4) {                                      // rare tail: deg>32 (~2e-4 of nodes)
        int e2 = 32 + q * 4;
        if (e2 < deg) {
            int4 sC = *(const int4*)(srcs + e2);
            process(sC, e2);
        }
    }

    // octet reduction: 14 partials x 3 xor rounds -> ALL lanes hold full sums
#pragma unroll
    for (int m = 1; m <= 4; m <<= 1) {
        d0 += __shfl_xor(d0, m);
        d1 += __shfl_xor(d1, m);
#pragma unroll
        for (int c = 0; c < HCQ; c++) acc[c] += __shfl_xor(acc[c], m);
    }

    float inv0 = 1.0f / (d0 + 1e-16f);
    float inv1 = 1.0f / (d1 + 1e-16f);
    float ov[HCQ];
#pragma unroll
    for (int c = 0; c < HCQ; c++)
        ov[c] = acc[c] * ((c < 6) ? inv0 : inv1) + sb[c];

    if (mode == 1) {
        if (q < 3) {                                  // 3 lanes x float4, coalesced
            float4* op = (float4*)(outF + (size_t)id * HCQ);
            op[q] = make_float4(ov[4 * q], ov[4 * q + 1], ov[4 * q + 2], ov[4 * q + 3]);
        }
        return;
    }
#pragma unroll
    for (int c = 0; c < HCQ; c++) ov[c] = fmaxf(ov[c], 0.f);
    // lane q<6 computes channel pair (2q, 2q+1); lanes 6,7 compute a dummy pair (cc=0)
    int cc = (q < 6) ? 2 * q : 0;
    float hv0 = 0.f, hv1 = 0.f;
#pragma unroll
    for (int k = 0; k < HCQ; k++) {
        hv0 += ov[k] * sW[k * HCQ + cc];
        hv1 += ov[k] * sW[k * HCQ + cc + 1];
    }
    float pe = hv0 * sas[cc] + hv1 * sas[cc + 1];
    float pf = hv0 * sad[cc] + hv1 * sad[cc + 1];
    if (q >= 6) { pe = 0.f; pf = 0.f; }
    // head sums across the octet (width-8 shuffles): head0 = lanes 0..2, head1 = lanes 3..5
    float e0h = (__shfl(pe, 0, 8) + __shfl(pe, 1, 8) + __shfl(pe, 2, 8)) * L2E;
    float e1h = (__shfl(pe, 3, 8) + __shfl(pe, 4, 8) + __shfl(pe, 5, 8)) * L2E;
    float f0h = (__shfl(pf, 0, 8) + __shfl(pf, 1, 8) + __shfl(pf, 2, 8)) * L2E;
    float f1h = (__shfl(pf, 3, 8) + __shfl(pf, 4, 8) + __shfl(pf, 5, 8)) * L2E;
    unsigned word;
    if (q < 6)      word = pack2(hv0, hv1);           // record words 0..5 (12 fp16 h)
    else if (q == 6) word = __float_as_uint(e0h);     // word 6: e0 (pre-scaled)
    else             word = __float_as_uint(e1h);     // word 7: e1 (pre-scaled)
    hrecO[(size_t)id * RECU + q] = word;              // 8 lanes x 4B = full 32B record, coalesced
    if (q == 0) ((float2*)edO)[id] = make_float2(f0h, f1h);
}

extern "C" void kernel_launch(void* const* d_in, const int* in_sizes, int n_in,
                              void* d_out, int out_size, void* d_ws, size_t ws_size,
                              hipStream_t stream) {
    const int*   nt  = (const int*)d_in[0];
    const float* req = (const float*)d_in[1];
    const float* ti  = (const float*)d_in[2];
    const int*   ei  = (const int*)d_in[3];
    const float* emb = (const float*)d_in[4];
    const float* W[4], *as_[4], *ad_[4], *bb[4];
    for (int l = 0; l < 4; l++) {
        W[l]   = (const float*)d_in[5 + l * 4 + 0];
        as_[l] = (const float*)d_in[5 + l * 4 + 1];
        ad_[l] = (const float*)d_in[5 + l * 4 + 2];
        bb[l]  = (const float*)d_in[5 + l * 4 + 3];
    }

    char* p = (char*)d_ws;
    auto alloc = [&](size_t bytes) -> void* {
        void* r = (void*)p;
        p += (bytes + 255) & ~(size_t)255;
        return r;
    };
    float*    stats = (float*)alloc((size_t)TT * 2 * 4);
    float*    part  = (float*)alloc((size_t)TT * SPB * 2 * 4);
    int*      cnt   = (int*)  alloc((size_t)TT * NN * 4);
    unsigned* hrecA = (unsigned*)alloc((size_t)TT * NN * RECU * 4);
    float*    edA   = (float*)alloc((size_t)TT * NN * 2 * 4);
    int*      gcnt  = (int*)  alloc((size_t)TT * NBKT * 4);
    // bke (28.9MB) dies at fillv2; hrecB/edB (16MB) born at edge pass 0 — alias them
    char*     ub    = (char*)alloc((size_t)TT * NBKT * BCAP * 4);
    unsigned* bke   = (unsigned*)ub;
    unsigned* hrecB = (unsigned*)ub;
    float*    edB   = (float*)(ub + (size_t)TT * NN * RECU * 4);
    int*      csr   = (int*)  alloc((size_t)TT * NN * CAP * 4);   // 76.8 MB, last

    hipMemsetAsync(gcnt, 0, (size_t)TT * NBKT * 4, stream);

    statsA<<<dim3(SPB, TT), 256, 0, stream>>>(req, part);
    statsB<<<TT, 64, 0, stream>>>(part, stats);

    scatF<<<dim3(NBE, TT), 256, 0, stream>>>(ei, gcnt, bke);
    size_t fillLds = (size_t)(BKT + BKT * CAP) * 4;   // 100,352 B < 160 KiB
    fillv2<<<dim3(NBKT, TT), 256, fillLds, stream>>>(bke, gcnt, cnt, csr);

    int ngrid = (TT * NN + 255) / 256;
    int egrid2 = 4 * NCB32;
    node0_kernel<<<ngrid, 256, 0, stream>>>(nt, req, ti, emb, W[0], as_[0], ad_[0], stats, hrecA, edA);
    // edge l reads buffer (l even -> A, odd -> B), writes the other; l=3 writes d_out
    edge_kernel<<<egrid2, 256, 0, stream>>>(cnt, csr, hrecA, edA, bb[0], W[1], as_[1], ad_[1],
                                            hrecB, edB, nullptr, 0);
    edge_kernel<<<egrid2, 256, 0, stream>>>(cnt, csr, hrecB, edB, bb[1], W[2], as_[2], ad_[2],
                                            hrecA, edA, nullptr, 0);
    edge_kernel<<<egrid2, 256, 0, stream>>>(cnt, csr, hrecA, edA, bb[2], W[3], as_[3], ad_[3],
                                            hrecB, edB, nullptr, 0);
    edge_kernel<<<egrid2, 256, 0, stream>>>(cnt, csr, hrecB, edB, bb[3], nullptr, nullptr, nullptr,
                                            nullptr, nullptr, (float*)d_out, 1);
}